// Round 4
// baseline (455.775 us; speedup 1.0000x reference)
//
#include <hip/hip_runtime.h>
#include <stdint.h>

#define T_TOK 2048
#define IDIM  1024
#define HID   4096
#define NE    8
#define BM    128
#define BN    128
#define BN2   64
#define BK    64
#define RMAX  5120
#define MAXTILES 40

typedef __bf16 bf16;
typedef bf16  bf16x8 __attribute__((ext_vector_type(8)));
typedef float f32x4  __attribute__((ext_vector_type(4)));

// ---- workspace meta layout (byte offsets) ----
#define WS_NTILES   128      // 1 int
#define WS_TILE_E   192      // 64 int
#define WS_TILE_R   448      // 64 int
#define WS_TOK_E    1024     // 2*T int
#define WS_TOK_W    17408    // 2*T float
#define WS_ROW_TOK  33792    // RMAX int (-1 = pad)
#define WS_ROW_W    54272    // RMAX float
#define WS_TOK_POS  74752    // 2*T int : position of (tok,slot) in row order
#define XG_OFF      131072   // gathered tokens, bf16 swizzled [RMAX][IDIM]

// bijective XCD-chunked remap (m204)
__device__ __forceinline__ int xcd_remap(int orig, int nwg) {
    int q = nwg >> 3, r = nwg & 7;
    int xcd = orig & 7, idx = orig >> 3;
    return (xcd < r ? xcd * (q + 1) : r * (q + 1) + (xcd - r) * q) + idx;
}

// ---------------- router: one wave per token (pure fp32, no atomics) ------
__global__ __launch_bounds__(256) void k_router(const float* __restrict__ xs,
                                                const float* __restrict__ Wg,
                                                int* __restrict__ tok_e,
                                                float* __restrict__ tok_w) {
    __shared__ float sWg[NE * IDIM];
    for (int i = threadIdx.x; i < NE * IDIM; i += 256) sWg[i] = Wg[i];
    __syncthreads();
    int wave = threadIdx.x >> 6, lane = threadIdx.x & 63;
    int t = blockIdx.x * 4 + wave;
    if (t >= T_TOK) return;
    float p[NE];
#pragma unroll
    for (int e = 0; e < NE; e++) p[e] = 0.f;
    for (int j = 0; j < IDIM / 64; j++) {
        float x = xs[(size_t)t * IDIM + j * 64 + lane];
#pragma unroll
        for (int e = 0; e < NE; e++)
            p[e] += x * sWg[e * IDIM + j * 64 + lane];
    }
#pragma unroll
    for (int e = 0; e < NE; e++) {
        float v = p[e];
        for (int off = 32; off > 0; off >>= 1) v += __shfl_down(v, off);
        p[e] = v;
    }
    if (lane == 0) {
        int e0 = 0; float l0 = p[0];
        for (int e = 1; e < NE; e++) if (p[e] > l0) { l0 = p[e]; e0 = e; }
        int e1 = -1; float l1 = -1e30f;
        for (int e = 0; e < NE; e++) if (e != e0 && p[e] > l1) { l1 = p[e]; e1 = e; }
        if (e1 < 0) e1 = (e0 + 1) & 7;
        float z = __expf(l1 - l0);              // <= 1
        tok_e[2 * t]     = e0;  tok_e[2 * t + 1] = e1;
        tok_w[2 * t]     = 1.f / (1.f + z);
        tok_w[2 * t + 1] = z / (1.f + z);
    }
}

// ---------------- setup: count + plan + scatter, one block -----------------
__global__ __launch_bounds__(256) void k_setup(int* __restrict__ w,
                                               float* __restrict__ wf) {
    __shared__ int cnt[NE];
    __shared__ int cur[NE];
    int tid = threadIdx.x;
    if (tid < NE) cnt[tid] = 0;
    for (int i = tid; i < RMAX; i += 256) w[WS_ROW_TOK / 4 + i] = -1;
    __syncthreads();
    for (int i = tid; i < 2 * T_TOK; i += 256)
        atomicAdd(&cnt[w[WS_TOK_E / 4 + i]], 1);
    __syncthreads();
    if (tid == 0) {
        int off = 0, nt = 0;
        for (int e = 0; e < NE; e++) {
            cur[e] = off;
            int nb = (cnt[e] + BM - 1) / BM;
            for (int b = 0; b < nb && nt < MAXTILES; b++) {
                w[WS_TILE_E / 4 + nt] = e;
                w[WS_TILE_R / 4 + nt] = off + b * BM;
                nt++;
            }
            off += nb * BM;
        }
        w[WS_NTILES / 4] = nt;
    }
    __syncthreads();
    for (int i = tid; i < 2 * T_TOK; i += 256) {
        int e   = w[WS_TOK_E / 4 + i];
        int pos = atomicAdd(&cur[e], 1);
        if (pos < RMAX) {
            w[WS_ROW_TOK / 4 + pos] = i >> 1;
            wf[WS_ROW_W / 4 + pos]  = wf[WS_TOK_W / 4 + i];
            w[WS_TOK_POS / 4 + i]   = pos;
        } else {
            w[WS_TOK_POS / 4 + i]   = 0;   // unreachable by construction
        }
    }
}

// pack helpers (fp32 -> bf16)
__device__ inline uint4 pack8(float4 a, float4 b) {
    union { bf16 h[8]; uint4 u; } pk;
    pk.h[0] = (bf16)a.x; pk.h[1] = (bf16)a.y; pk.h[2] = (bf16)a.z; pk.h[3] = (bf16)a.w;
    pk.h[4] = (bf16)b.x; pk.h[5] = (bf16)b.y; pk.h[6] = (bf16)b.z; pk.h[7] = (bf16)b.w;
    return pk.u;
}
__device__ inline uint32_t pack2(float a, float b) {
    union { bf16 h[2]; uint32_t u; } pk;
    pk.h[0] = (bf16)a; pk.h[1] = (bf16)b;
    return pk.u;
}

// async global->LDS, 16 B per lane; LDS dest must be wave-linear
__device__ __forceinline__ void g2l16(const bf16* g, bf16* l) {
    __builtin_amdgcn_global_load_lds(
        (const __attribute__((address_space(1))) void*)g,
        (__attribute__((address_space(3))) void*)l, 16, 0, 0);
}

// ---------------- gather tokens -> Xg (bf16, per-64 chunk XOR swizzle) -----
__global__ __launch_bounds__(256) void k_gather(const float* __restrict__ xs,
                                                const int* __restrict__ wsi,
                                                bf16* __restrict__ Xg) {
    int wv = threadIdx.x >> 6, lane = threadIdx.x & 63;
    int r = blockIdx.x * 4 + wv;
    int tok = wsi[WS_ROW_TOK / 4 + r];
#pragma unroll
    for (int i = 0; i < 2; i++) {
        int c = i * 64 + lane;               // 16B chunk index 0..127
        uint4 v;
        if (tok >= 0) {
            const float* g = xs + (size_t)tok * IDIM + c * 8;
            v = pack8(*(const float4*)g, *(const float4*)(g + 4));
        } else v = make_uint4(0u, 0u, 0u, 0u);
        int cs = (c & ~7) | ((c & 7) ^ (r & 7));
        *(uint4*)&Xg[(size_t)r * IDIM + cs * 8] = v;
    }
}

// ---------------- transpose-convert weights: dst[n][k](bf16,swz) = src[k][n]
// Each block: one 64-wide n-strip, tpb k-tiles (loop amortizes launch+LDS).
__global__ __launch_bounds__(256) void k_cvt(const float* __restrict__ src,
                                             bf16* __restrict__ dst,
                                             int ld_src, int k0, int n0, int KL,
                                             size_t s_estride, size_t d_estride,
                                             int tpb) {
    __shared__ bf16 sT[64 * 66];
    int e = blockIdx.z;
    const float* S = src + (size_t)e * s_estride;
    bf16* D = dst + (size_t)e * d_estride;
    int tn  = blockIdx.x;
    int tk0 = blockIdx.y * tpb;
    int t = threadIdx.x;
    for (int tt = 0; tt < tpb; tt++) {
        int tk = tk0 + tt;
        if (tt) __syncthreads();
#pragma unroll
        for (int i = 0; i < 4; i++) {
            int idx = t + i * 256;               // 0..1023
            int k = idx >> 4, n4 = (idx & 15) * 4;
            float4 v = *(const float4*)&S[(size_t)(k0 + tk * 64 + k) * ld_src +
                                          n0 + tn * 64 + n4];
            *(uint32_t*)&sT[k * 66 + n4]     = pack2(v.x, v.y);
            *(uint32_t*)&sT[k * 66 + n4 + 2] = pack2(v.z, v.w);
        }
        __syncthreads();
#pragma unroll
        for (int j = 0; j < 2; j++) {
            int idx = t + j * 256;               // 0..511
            int n = idx >> 3, kq = idx & 7;
            union { bf16 h[8]; uint4 u; } pk;
#pragma unroll
            for (int jj = 0; jj < 8; jj++) pk.h[jj] = sT[(kq * 8 + jj) * 66 + n];
            int ng = tn * 64 + n;
            int ch = kq ^ (ng & 7);              // swizzle within 64-elem segment
            *(uint4*)&D[(size_t)ng * KL + tk * 64 + ch * 8] = pk.u;
        }
    }
}

// ---------------- FFN1: H[:, :CW](swz) = relu(Xg @ W1t' + b1) --------------
// 128x128 tile, 2-phase double-buffered staging, LDS-repacked vector C-write.
__global__ __launch_bounds__(256) void k_ffn1n(const bf16* __restrict__ Xg,
                                               const bf16* __restrict__ W1t,
                                               const float* __restrict__ b1,
                                               const int* __restrict__ wsi,
                                               bf16* __restrict__ H,
                                               int h0, int CW) {
    int gx = gridDim.x;
    int orig = blockIdx.x + gx * blockIdx.y;
    int wgid = xcd_remap(orig, gx * gridDim.y);
    int bx = wgid % gx, tile = wgid / gx;
    if (tile >= wsi[WS_NTILES / 4]) return;
    int e    = wsi[WS_TILE_E / 4 + tile];
    int row0 = wsi[WS_TILE_R / 4 + tile];
    int n0   = bx * BN;                      // within chunk

    const bf16* Abase = Xg + (size_t)row0 * IDIM;
    const bf16* Bbase = W1t + ((size_t)e * CW + n0) * IDIM;

    __shared__ bf16 sA[2][BM * BK];          // 2 x 16 KB
    __shared__ bf16 sB[2][BN * BK];          // 2 x 16 KB

    int t = threadIdx.x, lane = t & 63;
    int wv = t >> 6, wx = wv & 1, wy = wv >> 1;
    int lm = lane & 15, q = lane >> 4;

    f32x4 acc[4][4];
#pragma unroll
    for (int i = 0; i < 4; i++)
#pragma unroll
        for (int j = 0; j < 4; j++) acc[i][j] = (f32x4){0.f, 0.f, 0.f, 0.f};

    auto stage = [&](int kc, int b) {
#pragma unroll
        for (int i = 0; i < 4; i++) {
            int s = t + i * 256;
            g2l16(Abase + (size_t)(s >> 3) * IDIM + kc * BK + (s & 7) * 8,
                  &sA[b][s * 8]);
        }
#pragma unroll
        for (int i = 0; i < 4; i++) {
            int s = t + i * 256;
            g2l16(Bbase + (size_t)(s >> 3) * IDIM + kc * BK + (s & 7) * 8,
                  &sB[b][s * 8]);
        }
    };

    stage(0, 0);
    __syncthreads();
    for (int kc = 0; kc < IDIM / BK; kc++) {
        int cur = kc & 1;
        if (kc + 1 < IDIM / BK) stage(kc + 1, cur ^ 1);
        const bf16* A = sA[cur];
        const bf16* B = sB[cur];
#pragma unroll
        for (int ks = 0; ks < 2; ks++) {
            bf16x8 aF[4], bF[4];
#pragma unroll
            for (int mt = 0; mt < 4; mt++) {
                int r = wy * 64 + mt * 16 + lm;
                aF[mt] = *(const bf16x8*)&A[r * BK + (((ks * 4 + q) ^ (r & 7)) * 8)];
            }
#pragma unroll
            for (int nt = 0; nt < 4; nt++) {
                int r = wx * 64 + nt * 16 + lm;
                bF[nt] = *(const bf16x8*)&B[r * BK + (((ks * 4 + q) ^ (r & 7)) * 8)];
            }
#pragma unroll
            for (int mt = 0; mt < 4; mt++)
#pragma unroll
                for (int nt = 0; nt < 4; nt++)
                    acc[mt][nt] = __builtin_amdgcn_mfma_f32_16x16x32_bf16(
                        aF[mt], bF[nt], acc[mt][nt], 0, 0, 0);
        }
        __syncthreads();   // publishes next buffer, protects current for reuse
    }

    // ---- epilogue: repack through LDS, store uint4 (coalesced) ----
    bf16* sC = &sA[0][0];                    // 32 KB = [128][128] bf16
#pragma unroll
    for (int nt = 0; nt < 4; nt++) {
        int col_l = wx * 64 + nt * 16 + lm;  // local col 0..127
        float bv  = b1[(size_t)e * HID + h0 + n0 + col_l];
#pragma unroll
        for (int mt = 0; mt < 4; mt++) {
#pragma unroll
            for (int r = 0; r < 4; r++) {
                int rloc = wy * 64 + mt * 16 + q * 4 + r;
                int rg   = row0 + rloc;
                float v = fmaxf(acc[mt][nt][r] + bv, 0.f);
                int sc = (col_l & ~63) | ((col_l & 63) ^ ((rg & 7) << 3));
                sC[rloc * BN + sc] = (bf16)v;
            }
        }
    }
    __syncthreads();
#pragma unroll
    for (int i = 0; i < 8; i++) {
        int u = t + i * 256;                 // 0..2047
        int row = u >> 4, c = u & 15;
        uint4 v = *(const uint4*)&sC[row * BN + c * 8];
        *(uint4*)&H[(size_t)(row0 + row) * CW + n0 + c * 8] = v;
    }
}

// -------- FFN2: Y[row] (+)= H @ W2t' (+ b2 on first chunk); 2-phase dbuf ---
__global__ __launch_bounds__(256) void k_ffn2y(const bf16* __restrict__ H,
                                               const bf16* __restrict__ W2t,
                                               const float* __restrict__ b2,
                                               const int* __restrict__ wsi,
                                               float* __restrict__ Y,
                                               int CW, int first) {
    int gx = gridDim.x;
    int orig = blockIdx.x + gx * blockIdx.y;
    int wgid = xcd_remap(orig, gx * gridDim.y);
    int bx = wgid % gx, tile = wgid / gx;
    if (tile >= wsi[WS_NTILES / 4]) return;
    int e    = wsi[WS_TILE_E / 4 + tile];
    int row0 = wsi[WS_TILE_R / 4 + tile];
    int n0   = bx * BN2;

    const bf16* Abase = H + (size_t)row0 * CW;
    const bf16* Bbase = W2t + ((size_t)e * IDIM + n0) * CW;

    __shared__ bf16 sA[2][BM * BK];          // 2 x 16 KB
    __shared__ bf16 sB[2][BN2 * BK];         // 2 x 8 KB

    int t = threadIdx.x, lane = t & 63;
    int wv = t >> 6, wx = wv & 1, wy = wv >> 1;
    int lm = lane & 15, q = lane >> 4;

    f32x4 acc[4][2];
#pragma unroll
    for (int i = 0; i < 4; i++)
#pragma unroll
        for (int j = 0; j < 2; j++) acc[i][j] = (f32x4){0.f, 0.f, 0.f, 0.f};

    auto stage = [&](int kc, int b) {
#pragma unroll
        for (int i = 0; i < 4; i++) {
            int s = t + i * 256;
            g2l16(Abase + (size_t)(s >> 3) * CW + kc * BK + (s & 7) * 8,
                  &sA[b][s * 8]);
        }
#pragma unroll
        for (int i = 0; i < 2; i++) {
            int s = t + i * 256;
            g2l16(Bbase + (size_t)(s >> 3) * CW + kc * BK + (s & 7) * 8,
                  &sB[b][s * 8]);
        }
    };

    int kiters = CW / BK;
    stage(0, 0);
    __syncthreads();
    for (int kc = 0; kc < kiters; kc++) {
        int cur = kc & 1;
        if (kc + 1 < kiters) stage(kc + 1, cur ^ 1);
        const bf16* A = sA[cur];
        const bf16* B = sB[cur];
#pragma unroll
        for (int ks = 0; ks < 2; ks++) {
            bf16x8 aF[4], bF[2];
#pragma unroll
            for (int mt = 0; mt < 4; mt++) {
                int r = wy * 64 + mt * 16 + lm;
                aF[mt] = *(const bf16x8*)&A[r * BK + (((ks * 4 + q) ^ (r & 7)) * 8)];
            }
#pragma unroll
            for (int nt = 0; nt < 2; nt++) {
                int r = wx * 32 + nt * 16 + lm;
                bF[nt] = *(const bf16x8*)&B[r * BK + (((ks * 4 + q) ^ (r & 7)) * 8)];
            }
#pragma unroll
            for (int mt = 0; mt < 4; mt++)
#pragma unroll
                for (int nt = 0; nt < 2; nt++)
                    acc[mt][nt] = __builtin_amdgcn_mfma_f32_16x16x32_bf16(
                        aF[mt], bF[nt], acc[mt][nt], 0, 0, 0);
        }
        __syncthreads();
    }

#pragma unroll
    for (int nt = 0; nt < 2; nt++) {
        int col  = n0 + wx * 32 + nt * 16 + lm;
        float bv = first ? b2[(size_t)e * IDIM + col] : 0.f;
#pragma unroll
        for (int mt = 0; mt < 4; mt++)
#pragma unroll
            for (int r = 0; r < 4; r++) {
                int rg = row0 + wy * 64 + mt * 16 + q * 4 + r;
                float* p = &Y[(size_t)rg * IDIM + col];
                float v  = acc[mt][nt][r] + bv;
                *p = first ? v : (*p + v);
            }
    }
}

// -------- combine: out[tok] = w0*Y[pos0] + w1*Y[pos1]  (one block/token) ---
__global__ __launch_bounds__(256) void k_combine(const float* __restrict__ Y,
                                                 const int* __restrict__ wsi,
                                                 const float* __restrict__ wsf,
                                                 float* __restrict__ out) {
    int tok = blockIdx.x;
    int p0 = wsi[WS_TOK_POS / 4 + 2 * tok];
    int p1 = wsi[WS_TOK_POS / 4 + 2 * tok + 1];
    float w0 = wsf[WS_TOK_W / 4 + 2 * tok];
    float w1 = wsf[WS_TOK_W / 4 + 2 * tok + 1];
    int c = threadIdx.x;                    // float4 index within row (256)
    const float4* y0 = (const float4*)(Y + (size_t)p0 * IDIM);
    const float4* y1 = (const float4*)(Y + (size_t)p1 * IDIM);
    float4 a = y0[c], b = y1[c];
    float4 r;
    r.x = w0 * a.x + w1 * b.x;
    r.y = w0 * a.y + w1 * b.y;
    r.z = w0 * a.z + w1 * b.z;
    r.w = w0 * a.w + w1 * b.w;
    ((float4*)(out + (size_t)tok * IDIM))[c] = r;
}

// ---------------- zero-workspace fallback (fp32) ----------------
__global__ __launch_bounds__(256) void k_fallback(const float* __restrict__ xs,
                                                  const float* __restrict__ Wg,
                                                  const float* __restrict__ W1,
                                                  const float* __restrict__ b1,
                                                  const float* __restrict__ W2,
                                                  const float* __restrict__ b2,
                                                  float* __restrict__ out) {
    __shared__ float xbuf[IDIM];
    __shared__ float hbuf[256];
    __shared__ float slog[NE];
    __shared__ int   sel[2];
    __shared__ float selw[2];

    int t   = blockIdx.x;
    int tid = threadIdx.x;

    for (int i = tid; i < IDIM; i += 256)
        xbuf[i] = xs[(size_t)t * IDIM + i];
    __syncthreads();
    {
        int e = tid >> 5, l = tid & 31;
        float p = 0.f;
        for (int d = l; d < IDIM; d += 32)
            p += xbuf[d] * Wg[e * IDIM + d];
        for (int off = 16; off > 0; off >>= 1) p += __shfl_down(p, off, 32);
        if (l == 0) slog[e] = p;
    }
    __syncthreads();
    if (tid == 0) {
        int e0 = 0; float l0 = slog[0];
        for (int e = 1; e < NE; e++) if (slog[e] > l0) { l0 = slog[e]; e0 = e; }
        int e1 = -1; float l1 = -1e30f;
        for (int e = 0; e < NE; e++) if (e != e0 && slog[e] > l1) { l1 = slog[e]; e1 = e; }
        if (e1 < 0) e1 = (e0 + 1) & 7;
        float z = __expf(l1 - l0);
        sel[0] = e0; sel[1] = e1;
        selw[0] = 1.f / (1.f + z);
        selw[1] = z / (1.f + z);
    }
    __syncthreads();

    float ytot[4] = {0.f, 0.f, 0.f, 0.f};
#pragma unroll
    for (int s = 0; s < 2; s++) {
        int   e = sel[s];
        float w = selw[s];
        const float* W1e = W1 + (size_t)e * IDIM * HID;
        const float* W2e = W2 + (size_t)e * HID * IDIM;
        float ys[4] = {0.f, 0.f, 0.f, 0.f};
        for (int hb = 0; hb < HID / 256; hb++) {
            int h = hb * 256 + tid;
            float acc = b1[e * HID + h];
            for (int d = 0; d < IDIM; d++)
                acc += xbuf[d] * W1e[(size_t)d * HID + h];
            __syncthreads();
            hbuf[tid] = fmaxf(acc, 0.f);
            __syncthreads();
            for (int hh = 0; hh < 256; hh++) {
                float hv = hbuf[hh];
                const float* wrow = W2e + (size_t)(hb * 256 + hh) * IDIM;
#pragma unroll
                for (int cc = 0; cc < 4; cc++)
                    ys[cc] += hv * wrow[cc * 256 + tid];
            }
        }
#pragma unroll
        for (int cc = 0; cc < 4; cc++)
            ytot[cc] += w * (ys[cc] + b2[e * IDIM + cc * 256 + tid]);
    }
#pragma unroll
    for (int cc = 0; cc < 4; cc++)
        out[(size_t)t * IDIM + cc * 256 + tid] = ytot[cc];
}

extern "C" void kernel_launch(void* const* d_in, const int* in_sizes, int n_in,
                              void* d_out, int out_size, void* d_ws, size_t ws_size,
                              hipStream_t stream) {
    int o = (n_in >= 7 && in_sizes[1] == 1) ? 1 : 0;
    const float* xs = (const float*)d_in[0];
    const float* Wg = (const float*)d_in[1 + o];
    const float* W1 = (const float*)d_in[2 + o];
    const float* b1 = (const float*)d_in[3 + o];
    const float* W2 = (const float*)d_in[4 + o];
    const float* b2 = (const float*)d_in[5 + o];
    float* out = (float*)d_out;

    // tier: meta + Xg + H(RMAX*CW) + Wshared(NE*CW*IDIM) + Y(RMAX*IDIM*4).
    size_t xg_sz = (size_t)RMAX * IDIM * 2;
    size_t y_sz  = (size_t)RMAX * IDIM * 4;
    int CW = 0;
    if (d_ws) {
        for (int c = HID; c >= 512; c >>= 1) {
            size_t need = (size_t)XG_OFF + xg_sz + (size_t)RMAX * c * 2 +
                          (size_t)NE * c * IDIM * 2 + y_sz;
            if (ws_size >= need) { CW = c; break; }
        }
    }
    if (!CW) {
        k_fallback<<<T_TOK, 256, 0, stream>>>(xs, Wg, W1, b1, W2, b2, out);
        return;
    }

    char*  ws  = (char*)d_ws;
    int*   wsi = (int*)d_ws;
    float* wsf = (float*)d_ws;
    bf16*  Xg  = (bf16*)(ws + XG_OFF);
    bf16*  Hb  = (bf16*)(ws + XG_OFF + xg_sz);
    bf16*  Wt  = (bf16*)(ws + XG_OFF + xg_sz + (size_t)RMAX * CW * 2);
    float* Yb  = (float*)(ws + XG_OFF + xg_sz + (size_t)RMAX * CW * 2 +
                          (size_t)NE * CW * IDIM * 2);

    k_router<<<T_TOK / 4, 256, 0, stream>>>(xs, Wg, wsi + WS_TOK_E / 4,
                                            wsf + WS_TOK_W / 4);
    k_setup<<<1, 256, 0, stream>>>(wsi, wsf);
    k_gather<<<RMAX / 4, 256, 0, stream>>>(xs, wsi, Xg);

    int HC = HID / CW;
    for (int c = 0; c < HC; c++) {
        // W1 chunk: src [k=IDIM][n=HID] -> Wt [n_local(CW)][k(IDIM)]
        {
            int ntn = CW / 64, ntk = IDIM / 64;
            int tpb = ntk;
            while (ntn * NE * (ntk / tpb) < 1024 && tpb > 1) tpb >>= 1;
            k_cvt<<<dim3(ntn, ntk / tpb, NE), 256, 0, stream>>>(
                W1, Wt, HID, 0, c * CW, IDIM,
                (size_t)IDIM * HID, (size_t)CW * IDIM, tpb);
        }
        k_ffn1n<<<dim3(CW / BN, MAXTILES), 256, 0, stream>>>(
            Xg, Wt, b1, wsi, Hb, c * CW, CW);
        // W2 chunk: src [k=HID][n=IDIM] -> Wt [n(IDIM)][k_local(CW)]
        {
            int ntn = IDIM / 64, ntk = CW / 64;
            int tpb = ntk;
            while (ntn * NE * (ntk / tpb) < 1024 && tpb > 1) tpb >>= 1;
            k_cvt<<<dim3(ntn, ntk / tpb, NE), 256, 0, stream>>>(
                W2, Wt, IDIM, c * CW, 0, CW,
                (size_t)HID * IDIM, (size_t)IDIM * CW, tpb);
        }
        k_ffn2y<<<dim3(IDIM / BN2, MAXTILES), 256, 0, stream>>>(
            Hb, Wt, b2, wsi, Yb, CW, c == 0 ? 1 : 0);
    }
    k_combine<<<T_TOK, 256, 0, stream>>>(Yb, wsi, wsf, out);
}

// Round 5
// 438.153 us; speedup vs baseline: 1.0402x; 1.0402x over previous
//
#include <hip/hip_runtime.h>
#include <stdint.h>

#define T_TOK 2048
#define IDIM  1024
#define HID   4096
#define NE    8
#define BM    128
#define BN    128
#define BN2   64
#define BK    64
#define RMAX  5120
#define MAXTILES 40

typedef __bf16 bf16;
typedef bf16  bf16x8 __attribute__((ext_vector_type(8)));
typedef float f32x4  __attribute__((ext_vector_type(4)));

// ---- workspace meta layout (byte offsets) ----
#define WS_NTILES   128      // 1 int
#define WS_TILE_E   192      // 64 int
#define WS_TILE_R   448      // 64 int
#define WS_TOK_E    1024     // 2*T int
#define WS_TOK_W    17408    // 2*T float
#define WS_ROW_TOK  33792    // RMAX int (-1 = pad)
#define WS_ROW_W    54272    // RMAX float
#define WS_TOK_POS  74752    // 2*T int : position of (tok,slot) in row order
#define XG_OFF      131072   // gathered tokens, bf16 swizzled [RMAX][IDIM]

// bijective XCD-chunked remap (m204)
__device__ __forceinline__ int xcd_remap(int orig, int nwg) {
    int q = nwg >> 3, r = nwg & 7;
    int xcd = orig & 7, idx = orig >> 3;
    return (xcd < r ? xcd * (q + 1) : r * (q + 1) + (xcd - r) * q) + idx;
}

// ---------------- router: one wave per token (pure fp32, no atomics) ------
__global__ __launch_bounds__(256) void k_router(const float* __restrict__ xs,
                                                const float* __restrict__ Wg,
                                                int* __restrict__ tok_e,
                                                float* __restrict__ tok_w) {
    __shared__ float sWg[NE * IDIM];
    for (int i = threadIdx.x; i < NE * IDIM; i += 256) sWg[i] = Wg[i];
    __syncthreads();
    int wave = threadIdx.x >> 6, lane = threadIdx.x & 63;
    int t = blockIdx.x * 4 + wave;
    if (t >= T_TOK) return;
    float p[NE];
#pragma unroll
    for (int e = 0; e < NE; e++) p[e] = 0.f;
    for (int j = 0; j < IDIM / 64; j++) {
        float x = xs[(size_t)t * IDIM + j * 64 + lane];
#pragma unroll
        for (int e = 0; e < NE; e++)
            p[e] += x * sWg[e * IDIM + j * 64 + lane];
    }
#pragma unroll
    for (int e = 0; e < NE; e++) {
        float v = p[e];
        for (int off = 32; off > 0; off >>= 1) v += __shfl_down(v, off);
        p[e] = v;
    }
    if (lane == 0) {
        int e0 = 0; float l0 = p[0];
        for (int e = 1; e < NE; e++) if (p[e] > l0) { l0 = p[e]; e0 = e; }
        int e1 = -1; float l1 = -1e30f;
        for (int e = 0; e < NE; e++) if (e != e0 && p[e] > l1) { l1 = p[e]; e1 = e; }
        if (e1 < 0) e1 = (e0 + 1) & 7;
        float z = __expf(l1 - l0);              // <= 1
        tok_e[2 * t]     = e0;  tok_e[2 * t + 1] = e1;
        tok_w[2 * t]     = 1.f / (1.f + z);
        tok_w[2 * t + 1] = z / (1.f + z);
    }
}

// ---------------- setup: count + plan + scatter, one block -----------------
__global__ __launch_bounds__(256) void k_setup(int* __restrict__ w,
                                               float* __restrict__ wf) {
    __shared__ int cnt[NE];
    __shared__ int cur[NE];
    int tid = threadIdx.x;
    if (tid < NE) cnt[tid] = 0;
    for (int i = tid; i < RMAX; i += 256) w[WS_ROW_TOK / 4 + i] = -1;
    __syncthreads();
    for (int i = tid; i < 2 * T_TOK; i += 256)
        atomicAdd(&cnt[w[WS_TOK_E / 4 + i]], 1);
    __syncthreads();
    if (tid == 0) {
        int off = 0, nt = 0;
        for (int e = 0; e < NE; e++) {
            cur[e] = off;
            int nb = (cnt[e] + BM - 1) / BM;
            for (int b = 0; b < nb && nt < MAXTILES; b++) {
                w[WS_TILE_E / 4 + nt] = e;
                w[WS_TILE_R / 4 + nt] = off + b * BM;
                nt++;
            }
            off += nb * BM;
        }
        w[WS_NTILES / 4] = nt;
    }
    __syncthreads();
    for (int i = tid; i < 2 * T_TOK; i += 256) {
        int e   = w[WS_TOK_E / 4 + i];
        int pos = atomicAdd(&cur[e], 1);
        if (pos < RMAX) {
            w[WS_ROW_TOK / 4 + pos] = i >> 1;
            wf[WS_ROW_W / 4 + pos]  = wf[WS_TOK_W / 4 + i];
            w[WS_TOK_POS / 4 + i]   = pos;
        } else {
            w[WS_TOK_POS / 4 + i]   = 0;   // unreachable by construction
        }
    }
}

// pack helpers (fp32 -> bf16)
__device__ inline uint4 pack8(float4 a, float4 b) {
    union { bf16 h[8]; uint4 u; } pk;
    pk.h[0] = (bf16)a.x; pk.h[1] = (bf16)a.y; pk.h[2] = (bf16)a.z; pk.h[3] = (bf16)a.w;
    pk.h[4] = (bf16)b.x; pk.h[5] = (bf16)b.y; pk.h[6] = (bf16)b.z; pk.h[7] = (bf16)b.w;
    return pk.u;
}
__device__ inline uint32_t pack2(float a, float b) {
    union { bf16 h[2]; uint32_t u; } pk;
    pk.h[0] = (bf16)a; pk.h[1] = (bf16)b;
    return pk.u;
}

// async global->LDS, 16 B per lane; LDS dest must be wave-linear
__device__ __forceinline__ void g2l16(const bf16* g, bf16* l) {
    __builtin_amdgcn_global_load_lds(
        (const __attribute__((address_space(1))) void*)g,
        (__attribute__((address_space(3))) void*)l, 16, 0, 0);
}

// ---------------- gather tokens -> Xg (bf16, per-64 chunk XOR swizzle) -----
__global__ __launch_bounds__(256) void k_gather(const float* __restrict__ xs,
                                                const int* __restrict__ wsi,
                                                bf16* __restrict__ Xg) {
    int wv = threadIdx.x >> 6, lane = threadIdx.x & 63;
    int r = blockIdx.x * 4 + wv;
    int tok = wsi[WS_ROW_TOK / 4 + r];
#pragma unroll
    for (int i = 0; i < 2; i++) {
        int c = i * 64 + lane;               // 16B chunk index 0..127
        uint4 v;
        if (tok >= 0) {
            const float* g = xs + (size_t)tok * IDIM + c * 8;
            v = pack8(*(const float4*)g, *(const float4*)(g + 4));
        } else v = make_uint4(0u, 0u, 0u, 0u);
        int cs = (c & ~7) | ((c & 7) ^ (r & 7));
        *(uint4*)&Xg[(size_t)r * IDIM + cs * 8] = v;
    }
}

// ---------------- transpose-convert weights: dst[n][k](bf16,swz) = src[k][n]
// Each block: one 64-wide n-strip, tpb k-tiles (loop amortizes launch+LDS).
__global__ __launch_bounds__(256) void k_cvt(const float* __restrict__ src,
                                             bf16* __restrict__ dst,
                                             int ld_src, int k0, int n0, int KL,
                                             size_t s_estride, size_t d_estride,
                                             int tpb) {
    __shared__ bf16 sT[64 * 66];
    int e = blockIdx.z;
    const float* S = src + (size_t)e * s_estride;
    bf16* D = dst + (size_t)e * d_estride;
    int tn  = blockIdx.x;
    int tk0 = blockIdx.y * tpb;
    int t = threadIdx.x;
    for (int tt = 0; tt < tpb; tt++) {
        int tk = tk0 + tt;
        if (tt) __syncthreads();
#pragma unroll
        for (int i = 0; i < 4; i++) {
            int idx = t + i * 256;               // 0..1023
            int k = idx >> 4, n4 = (idx & 15) * 4;
            float4 v = *(const float4*)&S[(size_t)(k0 + tk * 64 + k) * ld_src +
                                          n0 + tn * 64 + n4];
            *(uint32_t*)&sT[k * 66 + n4]     = pack2(v.x, v.y);
            *(uint32_t*)&sT[k * 66 + n4 + 2] = pack2(v.z, v.w);
        }
        __syncthreads();
#pragma unroll
        for (int j = 0; j < 2; j++) {
            int idx = t + j * 256;               // 0..511
            int n = idx >> 3, kq = idx & 7;
            union { bf16 h[8]; uint4 u; } pk;
#pragma unroll
            for (int jj = 0; jj < 8; jj++) pk.h[jj] = sT[(kq * 8 + jj) * 66 + n];
            int ng = tn * 64 + n;
            int ch = kq ^ (ng & 7);              // swizzle within 64-elem segment
            *(uint4*)&D[(size_t)ng * KL + tk * 64 + ch * 8] = pk.u;
        }
    }
}

// ---------------- FFN1: H[:, :CW](swz) = relu(Xg @ W1t' + b1) --------------
// 128x128 tile, single-buffer staging (32 KB -> 5 blk/CU), LDS-repacked
// vector C-write reusing the same 32 KB.
__global__ __launch_bounds__(256) void k_ffn1n(const bf16* __restrict__ Xg,
                                               const bf16* __restrict__ W1t,
                                               const float* __restrict__ b1,
                                               const int* __restrict__ wsi,
                                               bf16* __restrict__ H,
                                               int h0, int CW) {
    int gx = gridDim.x;
    int orig = blockIdx.x + gx * blockIdx.y;
    int wgid = xcd_remap(orig, gx * gridDim.y);
    int bx = wgid % gx, tile = wgid / gx;
    if (tile >= wsi[WS_NTILES / 4]) return;
    int e    = wsi[WS_TILE_E / 4 + tile];
    int row0 = wsi[WS_TILE_R / 4 + tile];
    int n0   = bx * BN;                      // within chunk

    const bf16* Abase = Xg + (size_t)row0 * IDIM;
    const bf16* Bbase = W1t + ((size_t)e * CW + n0) * IDIM;

    __shared__ bf16 smem[BM * BK + BN * BK]; // 32 KB total
    bf16* sA = smem;
    bf16* sB = smem + BM * BK;

    int t = threadIdx.x, lane = t & 63;
    int wv = t >> 6, wx = wv & 1, wy = wv >> 1;
    int lm = lane & 15, q = lane >> 4;

    f32x4 acc[4][4];
#pragma unroll
    for (int i = 0; i < 4; i++)
#pragma unroll
        for (int j = 0; j < 4; j++) acc[i][j] = (f32x4){0.f, 0.f, 0.f, 0.f};

    for (int kc = 0; kc < IDIM / BK; kc++) {
        if (kc) __syncthreads();
#pragma unroll
        for (int i = 0; i < 4; i++) {
            int s = t + i * 256;
            g2l16(Abase + (size_t)(s >> 3) * IDIM + kc * BK + (s & 7) * 8,
                  &sA[s * 8]);
        }
#pragma unroll
        for (int i = 0; i < 4; i++) {
            int s = t + i * 256;
            g2l16(Bbase + (size_t)(s >> 3) * IDIM + kc * BK + (s & 7) * 8,
                  &sB[s * 8]);
        }
        __syncthreads();
#pragma unroll
        for (int ks = 0; ks < 2; ks++) {
            bf16x8 aF[4], bF[4];
#pragma unroll
            for (int mt = 0; mt < 4; mt++) {
                int r = wy * 64 + mt * 16 + lm;
                aF[mt] = *(const bf16x8*)&sA[r * BK + (((ks * 4 + q) ^ (r & 7)) * 8)];
            }
#pragma unroll
            for (int nt = 0; nt < 4; nt++) {
                int r = wx * 64 + nt * 16 + lm;
                bF[nt] = *(const bf16x8*)&sB[r * BK + (((ks * 4 + q) ^ (r & 7)) * 8)];
            }
#pragma unroll
            for (int mt = 0; mt < 4; mt++)
#pragma unroll
                for (int nt = 0; nt < 4; nt++)
                    acc[mt][nt] = __builtin_amdgcn_mfma_f32_16x16x32_bf16(
                        aF[mt], bF[nt], acc[mt][nt], 0, 0, 0);
        }
    }

    // ---- epilogue: repack through LDS (same 32 KB), store uint4 coalesced --
    __syncthreads();
    bf16* sC = smem;                         // [128][128] bf16 = 32 KB
#pragma unroll
    for (int nt = 0; nt < 4; nt++) {
        int col_l = wx * 64 + nt * 16 + lm;  // local col 0..127
        float bv  = b1[(size_t)e * HID + h0 + n0 + col_l];
#pragma unroll
        for (int mt = 0; mt < 4; mt++) {
#pragma unroll
            for (int r = 0; r < 4; r++) {
                int rloc = wy * 64 + mt * 16 + q * 4 + r;
                int rg   = row0 + rloc;
                float v = fmaxf(acc[mt][nt][r] + bv, 0.f);
                int sc = (col_l & ~63) | ((col_l & 63) ^ ((rg & 7) << 3));
                sC[rloc * BN + sc] = (bf16)v;
            }
        }
    }
    __syncthreads();
#pragma unroll
    for (int i = 0; i < 8; i++) {
        int u = t + i * 256;                 // 0..2047
        int row = u >> 4, c = u & 15;
        uint4 v = *(const uint4*)&sC[row * BN + c * 8];
        *(uint4*)&H[(size_t)(row0 + row) * CW + n0 + c * 8] = v;
    }
}

// -------- FFN2: Y[row] (+)= H @ W2t' (+ b2 on first chunk); single-buffer --
__global__ __launch_bounds__(256) void k_ffn2y(const bf16* __restrict__ H,
                                               const bf16* __restrict__ W2t,
                                               const float* __restrict__ b2,
                                               const int* __restrict__ wsi,
                                               float* __restrict__ Y,
                                               int CW, int first) {
    int gx = gridDim.x;
    int orig = blockIdx.x + gx * blockIdx.y;
    int wgid = xcd_remap(orig, gx * gridDim.y);
    int bx = wgid % gx, tile = wgid / gx;
    if (tile >= wsi[WS_NTILES / 4]) return;
    int e    = wsi[WS_TILE_E / 4 + tile];
    int row0 = wsi[WS_TILE_R / 4 + tile];
    int n0   = bx * BN2;

    const bf16* Abase = H + (size_t)row0 * CW;
    const bf16* Bbase = W2t + ((size_t)e * IDIM + n0) * CW;

    __shared__ bf16 sA[BM * BK];             // 16 KB
    __shared__ bf16 sB[BN2 * BK];            // 8 KB

    int t = threadIdx.x, lane = t & 63;
    int wv = t >> 6, wx = wv & 1, wy = wv >> 1;
    int lm = lane & 15, q = lane >> 4;

    f32x4 acc[4][2];
#pragma unroll
    for (int i = 0; i < 4; i++)
#pragma unroll
        for (int j = 0; j < 2; j++) acc[i][j] = (f32x4){0.f, 0.f, 0.f, 0.f};

    int kiters = CW / BK;
    for (int kc = 0; kc < kiters; kc++) {
        if (kc) __syncthreads();
#pragma unroll
        for (int i = 0; i < 4; i++) {
            int s = t + i * 256;
            g2l16(Abase + (size_t)(s >> 3) * CW + kc * BK + (s & 7) * 8,
                  &sA[s * 8]);
        }
#pragma unroll
        for (int i = 0; i < 2; i++) {
            int s = t + i * 256;
            g2l16(Bbase + (size_t)(s >> 3) * CW + kc * BK + (s & 7) * 8,
                  &sB[s * 8]);
        }
        __syncthreads();
#pragma unroll
        for (int ks = 0; ks < 2; ks++) {
            bf16x8 aF[4], bF[2];
#pragma unroll
            for (int mt = 0; mt < 4; mt++) {
                int r = wy * 64 + mt * 16 + lm;
                aF[mt] = *(const bf16x8*)&sA[r * BK + (((ks * 4 + q) ^ (r & 7)) * 8)];
            }
#pragma unroll
            for (int nt = 0; nt < 2; nt++) {
                int r = wx * 32 + nt * 16 + lm;
                bF[nt] = *(const bf16x8*)&sB[r * BK + (((ks * 4 + q) ^ (r & 7)) * 8)];
            }
#pragma unroll
            for (int mt = 0; mt < 4; mt++)
#pragma unroll
                for (int nt = 0; nt < 2; nt++)
                    acc[mt][nt] = __builtin_amdgcn_mfma_f32_16x16x32_bf16(
                        aF[mt], bF[nt], acc[mt][nt], 0, 0, 0);
        }
    }

#pragma unroll
    for (int nt = 0; nt < 2; nt++) {
        int col  = n0 + wx * 32 + nt * 16 + lm;
        float bv = first ? b2[(size_t)e * IDIM + col] : 0.f;
#pragma unroll
        for (int mt = 0; mt < 4; mt++)
#pragma unroll
            for (int r = 0; r < 4; r++) {
                int rg = row0 + wy * 64 + mt * 16 + q * 4 + r;
                float* p = &Y[(size_t)rg * IDIM + col];
                float v  = acc[mt][nt][r] + bv;
                *p = first ? v : (*p + v);
            }
    }
}

// -------- combine: out[tok] = w0*Y[pos0] + w1*Y[pos1]  (one block/token) ---
__global__ __launch_bounds__(256) void k_combine(const float* __restrict__ Y,
                                                 const int* __restrict__ wsi,
                                                 const float* __restrict__ wsf,
                                                 float* __restrict__ out) {
    int tok = blockIdx.x;
    int p0 = wsi[WS_TOK_POS / 4 + 2 * tok];
    int p1 = wsi[WS_TOK_POS / 4 + 2 * tok + 1];
    float w0 = wsf[WS_TOK_W / 4 + 2 * tok];
    float w1 = wsf[WS_TOK_W / 4 + 2 * tok + 1];
    int c = threadIdx.x;                    // float4 index within row (256)
    const float4* y0 = (const float4*)(Y + (size_t)p0 * IDIM);
    const float4* y1 = (const float4*)(Y + (size_t)p1 * IDIM);
    float4 a = y0[c], b = y1[c];
    float4 r;
    r.x = w0 * a.x + w1 * b.x;
    r.y = w0 * a.y + w1 * b.y;
    r.z = w0 * a.z + w1 * b.z;
    r.w = w0 * a.w + w1 * b.w;
    ((float4*)(out + (size_t)tok * IDIM))[c] = r;
}

// ---------------- zero-workspace fallback (fp32) ----------------
__global__ __launch_bounds__(256) void k_fallback(const float* __restrict__ xs,
                                                  const float* __restrict__ Wg,
                                                  const float* __restrict__ W1,
                                                  const float* __restrict__ b1,
                                                  const float* __restrict__ W2,
                                                  const float* __restrict__ b2,
                                                  float* __restrict__ out) {
    __shared__ float xbuf[IDIM];
    __shared__ float hbuf[256];
    __shared__ float slog[NE];
    __shared__ int   sel[2];
    __shared__ float selw[2];

    int t   = blockIdx.x;
    int tid = threadIdx.x;

    for (int i = tid; i < IDIM; i += 256)
        xbuf[i] = xs[(size_t)t * IDIM + i];
    __syncthreads();
    {
        int e = tid >> 5, l = tid & 31;
        float p = 0.f;
        for (int d = l; d < IDIM; d += 32)
            p += xbuf[d] * Wg[e * IDIM + d];
        for (int off = 16; off > 0; off >>= 1) p += __shfl_down(p, off, 32);
        if (l == 0) slog[e] = p;
    }
    __syncthreads();
    if (tid == 0) {
        int e0 = 0; float l0 = slog[0];
        for (int e = 1; e < NE; e++) if (slog[e] > l0) { l0 = slog[e]; e0 = e; }
        int e1 = -1; float l1 = -1e30f;
        for (int e = 0; e < NE; e++) if (e != e0 && slog[e] > l1) { l1 = slog[e]; e1 = e; }
        if (e1 < 0) e1 = (e0 + 1) & 7;
        float z = __expf(l1 - l0);
        sel[0] = e0; sel[1] = e1;
        selw[0] = 1.f / (1.f + z);
        selw[1] = z / (1.f + z);
    }
    __syncthreads();

    float ytot[4] = {0.f, 0.f, 0.f, 0.f};
#pragma unroll
    for (int s = 0; s < 2; s++) {
        int   e = sel[s];
        float w = selw[s];
        const float* W1e = W1 + (size_t)e * IDIM * HID;
        const float* W2e = W2 + (size_t)e * HID * IDIM;
        float ys[4] = {0.f, 0.f, 0.f, 0.f};
        for (int hb = 0; hb < HID / 256; hb++) {
            int h = hb * 256 + tid;
            float acc = b1[e * HID + h];
            for (int d = 0; d < IDIM; d++)
                acc += xbuf[d] * W1e[(size_t)d * HID + h];
            __syncthreads();
            hbuf[tid] = fmaxf(acc, 0.f);
            __syncthreads();
            for (int hh = 0; hh < 256; hh++) {
                float hv = hbuf[hh];
                const float* wrow = W2e + (size_t)(hb * 256 + hh) * IDIM;
#pragma unroll
                for (int cc = 0; cc < 4; cc++)
                    ys[cc] += hv * wrow[cc * 256 + tid];
            }
        }
#pragma unroll
        for (int cc = 0; cc < 4; cc++)
            ytot[cc] += w * (ys[cc] + b2[e * IDIM + cc * 256 + tid]);
    }
#pragma unroll
    for (int cc = 0; cc < 4; cc++)
        out[(size_t)t * IDIM + cc * 256 + tid] = ytot[cc];
}

extern "C" void kernel_launch(void* const* d_in, const int* in_sizes, int n_in,
                              void* d_out, int out_size, void* d_ws, size_t ws_size,
                              hipStream_t stream) {
    int o = (n_in >= 7 && in_sizes[1] == 1) ? 1 : 0;
    const float* xs = (const float*)d_in[0];
    const float* Wg = (const float*)d_in[1 + o];
    const float* W1 = (const float*)d_in[2 + o];
    const float* b1 = (const float*)d_in[3 + o];
    const float* W2 = (const float*)d_in[4 + o];
    const float* b2 = (const float*)d_in[5 + o];
    float* out = (float*)d_out;

    // tier: meta + Xg + H(RMAX*CW) + Wshared(NE*CW*IDIM) + Y(RMAX*IDIM*4).
    size_t xg_sz = (size_t)RMAX * IDIM * 2;
    size_t y_sz  = (size_t)RMAX * IDIM * 4;
    int CW = 0;
    if (d_ws) {
        for (int c = HID; c >= 512; c >>= 1) {
            size_t need = (size_t)XG_OFF + xg_sz + (size_t)RMAX * c * 2 +
                          (size_t)NE * c * IDIM * 2 + y_sz;
            if (ws_size >= need) { CW = c; break; }
        }
    }
    if (!CW) {
        k_fallback<<<T_TOK, 256, 0, stream>>>(xs, Wg, W1, b1, W2, b2, out);
        return;
    }

    char*  ws  = (char*)d_ws;
    int*   wsi = (int*)d_ws;
    float* wsf = (float*)d_ws;
    bf16*  Xg  = (bf16*)(ws + XG_OFF);
    bf16*  Hb  = (bf16*)(ws + XG_OFF + xg_sz);
    bf16*  Wt  = (bf16*)(ws + XG_OFF + xg_sz + (size_t)RMAX * CW * 2);
    float* Yb  = (float*)(ws + XG_OFF + xg_sz + (size_t)RMAX * CW * 2 +
                          (size_t)NE * CW * IDIM * 2);

    k_router<<<T_TOK / 4, 256, 0, stream>>>(xs, Wg, wsi + WS_TOK_E / 4,
                                            wsf + WS_TOK_W / 4);
    k_setup<<<1, 256, 0, stream>>>(wsi, wsf);
    k_gather<<<RMAX / 4, 256, 0, stream>>>(xs, wsi, Xg);

    int HC = HID / CW;
    for (int c = 0; c < HC; c++) {
        // W1 chunk: src [k=IDIM][n=HID] -> Wt [n_local(CW)][k(IDIM)]
        {
            int ntn = CW / 64, ntk = IDIM / 64;
            int tpb = ntk;
            while (ntn * NE * (ntk / tpb) < 1024 && tpb > 1) tpb >>= 1;
            k_cvt<<<dim3(ntn, ntk / tpb, NE), 256, 0, stream>>>(
                W1, Wt, HID, 0, c * CW, IDIM,
                (size_t)IDIM * HID, (size_t)CW * IDIM, tpb);
        }
        k_ffn1n<<<dim3(CW / BN, MAXTILES), 256, 0, stream>>>(
            Xg, Wt, b1, wsi, Hb, c * CW, CW);
        // W2 chunk: src [k=HID][n=IDIM] -> Wt [n(IDIM)][k_local(CW)]
        {
            int ntn = IDIM / 64, ntk = CW / 64;
            int tpb = ntk;
            while (ntn * NE * (ntk / tpb) < 1024 && tpb > 1) tpb >>= 1;
            k_cvt<<<dim3(ntn, ntk / tpb, NE), 256, 0, stream>>>(
                W2, Wt, IDIM, c * CW, 0, CW,
                (size_t)HID * IDIM, (size_t)IDIM * CW, tpb);
        }
        k_ffn2y<<<dim3(IDIM / BN2, MAXTILES), 256, 0, stream>>>(
            Hb, Wt, b2, wsi, Yb, CW, c == 0 ? 1 : 0);
    }
    k_combine<<<T_TOK, 256, 0, stream>>>(Yb, wsi, wsf, out);
}

// Round 7
// 437.663 us; speedup vs baseline: 1.0414x; 1.0011x over previous
//
#include <hip/hip_runtime.h>
#include <stdint.h>

#define T_TOK 2048
#define IDIM  1024
#define HID   4096
#define NE    8
#define BM    128
#define BN    128
#define BN2   64
#define BK    64
#define RMAX  5120
#define MAXTILES 40

typedef __bf16 bf16;
typedef bf16  bf16x8 __attribute__((ext_vector_type(8)));
typedef float f32x4  __attribute__((ext_vector_type(4)));

// ---- workspace meta layout (byte offsets) ----
#define WS_NTILES   128      // 1 int
#define WS_TILE_E   192      // 64 int
#define WS_TILE_R   448      // 64 int
#define WS_TOK_E    1024     // 2*T int
#define WS_TOK_W    17408    // 2*T float
#define WS_ROW_TOK  33792    // RMAX int (-1 = pad)
#define WS_ROW_W    54272    // RMAX float
#define WS_TOK_POS  74752    // 2*T int : position of (tok,slot) in row order
#define XG_OFF      131072   // gathered tokens, bf16 swizzled [RMAX][IDIM]

// bijective XCD-chunked remap (m204)
__device__ __forceinline__ int xcd_remap(int orig, int nwg) {
    int q = nwg >> 3, r = nwg & 7;
    int xcd = orig & 7, idx = orig >> 3;
    return (xcd < r ? xcd * (q + 1) : r * (q + 1) + (xcd - r) * q) + idx;
}

// ---------------- router: one wave per token (pure fp32, no atomics) ------
__global__ __launch_bounds__(256) void k_router(const float* __restrict__ xs,
                                                const float* __restrict__ Wg,
                                                int* __restrict__ tok_e,
                                                float* __restrict__ tok_w) {
    __shared__ float sWg[NE * IDIM];
    for (int i = threadIdx.x; i < NE * IDIM; i += 256) sWg[i] = Wg[i];
    __syncthreads();
    int wave = threadIdx.x >> 6, lane = threadIdx.x & 63;
    int t = blockIdx.x * 4 + wave;
    if (t >= T_TOK) return;
    float p[NE];
#pragma unroll
    for (int e = 0; e < NE; e++) p[e] = 0.f;
    for (int j = 0; j < IDIM / 64; j++) {
        float x = xs[(size_t)t * IDIM + j * 64 + lane];
#pragma unroll
        for (int e = 0; e < NE; e++)
            p[e] += x * sWg[e * IDIM + j * 64 + lane];
    }
#pragma unroll
    for (int e = 0; e < NE; e++) {
        float v = p[e];
        for (int off = 32; off > 0; off >>= 1) v += __shfl_down(v, off);
        p[e] = v;
    }
    if (lane == 0) {
        int e0 = 0; float l0 = p[0];
        for (int e = 1; e < NE; e++) if (p[e] > l0) { l0 = p[e]; e0 = e; }
        int e1 = -1; float l1 = -1e30f;
        for (int e = 0; e < NE; e++) if (e != e0 && p[e] > l1) { l1 = p[e]; e1 = e; }
        if (e1 < 0) e1 = (e0 + 1) & 7;
        float z = __expf(l1 - l0);              // <= 1
        tok_e[2 * t]     = e0;  tok_e[2 * t + 1] = e1;
        tok_w[2 * t]     = 1.f / (1.f + z);
        tok_w[2 * t + 1] = z / (1.f + z);
    }
}

// ---------------- setup: count + plan + scatter, one block -----------------
__global__ __launch_bounds__(256) void k_setup(int* __restrict__ w,
                                               float* __restrict__ wf) {
    __shared__ int cnt[NE];
    __shared__ int cur[NE];
    int tid = threadIdx.x;
    if (tid < NE) cnt[tid] = 0;
    for (int i = tid; i < RMAX; i += 256) w[WS_ROW_TOK / 4 + i] = -1;
    __syncthreads();
    for (int i = tid; i < 2 * T_TOK; i += 256)
        atomicAdd(&cnt[w[WS_TOK_E / 4 + i]], 1);
    __syncthreads();
    if (tid == 0) {
        int off = 0, nt = 0;
        for (int e = 0; e < NE; e++) {
            cur[e] = off;
            int nb = (cnt[e] + BM - 1) / BM;
            for (int b = 0; b < nb && nt < MAXTILES; b++) {
                w[WS_TILE_E / 4 + nt] = e;
                w[WS_TILE_R / 4 + nt] = off + b * BM;
                nt++;
            }
            off += nb * BM;
        }
        w[WS_NTILES / 4] = nt;
    }
    __syncthreads();
    for (int i = tid; i < 2 * T_TOK; i += 256) {
        int e   = w[WS_TOK_E / 4 + i];
        int pos = atomicAdd(&cur[e], 1);
        if (pos < RMAX) {
            w[WS_ROW_TOK / 4 + pos] = i >> 1;
            wf[WS_ROW_W / 4 + pos]  = wf[WS_TOK_W / 4 + i];
            w[WS_TOK_POS / 4 + i]   = pos;
        } else {
            w[WS_TOK_POS / 4 + i]   = 0;   // unreachable by construction
        }
    }
}

// pack helpers (fp32 -> bf16)
__device__ inline uint4 pack8(float4 a, float4 b) {
    union { bf16 h[8]; uint4 u; } pk;
    pk.h[0] = (bf16)a.x; pk.h[1] = (bf16)a.y; pk.h[2] = (bf16)a.z; pk.h[3] = (bf16)a.w;
    pk.h[4] = (bf16)b.x; pk.h[5] = (bf16)b.y; pk.h[6] = (bf16)b.z; pk.h[7] = (bf16)b.w;
    return pk.u;
}
__device__ inline uint32_t pack2(float a, float b) {
    union { bf16 h[2]; uint32_t u; } pk;
    pk.h[0] = (bf16)a; pk.h[1] = (bf16)b;
    return pk.u;
}

// async global->LDS, 16 B per lane; LDS dest must be wave-linear
__device__ __forceinline__ void g2l16(const bf16* g, bf16* l) {
    __builtin_amdgcn_global_load_lds(
        (const __attribute__((address_space(1))) void*)g,
        (__attribute__((address_space(3))) void*)l, 16, 0, 0);
}

// ---------------- gather tokens -> Xg (bf16, per-64 chunk XOR swizzle) -----
__global__ __launch_bounds__(256) void k_gather(const float* __restrict__ xs,
                                                const int* __restrict__ wsi,
                                                bf16* __restrict__ Xg) {
    int wv = threadIdx.x >> 6, lane = threadIdx.x & 63;
    int r = blockIdx.x * 4 + wv;
    int tok = wsi[WS_ROW_TOK / 4 + r];
#pragma unroll
    for (int i = 0; i < 2; i++) {
        int c = i * 64 + lane;               // 16B chunk index 0..127
        uint4 v;
        if (tok >= 0) {
            const float* g = xs + (size_t)tok * IDIM + c * 8;
            v = pack8(*(const float4*)g, *(const float4*)(g + 4));
        } else v = make_uint4(0u, 0u, 0u, 0u);
        int cs = (c & ~7) | ((c & 7) ^ (r & 7));
        *(uint4*)&Xg[(size_t)r * IDIM + cs * 8] = v;
    }
}

// ---------------- transpose-convert weights: dst[n][k](bf16,swz) = src[k][n]
// Each block: one 64-wide n-strip, tpb k-tiles (loop amortizes launch+LDS).
__global__ __launch_bounds__(256) void k_cvt(const float* __restrict__ src,
                                             bf16* __restrict__ dst,
                                             int ld_src, int k0, int n0, int KL,
                                             size_t s_estride, size_t d_estride,
                                             int tpb) {
    __shared__ bf16 sT[64 * 66];
    int e = blockIdx.z;
    const float* S = src + (size_t)e * s_estride;
    bf16* D = dst + (size_t)e * d_estride;
    int tn  = blockIdx.x;
    int tk0 = blockIdx.y * tpb;
    int t = threadIdx.x;
    for (int tt = 0; tt < tpb; tt++) {
        int tk = tk0 + tt;
        if (tt) __syncthreads();
#pragma unroll
        for (int i = 0; i < 4; i++) {
            int idx = t + i * 256;               // 0..1023
            int k = idx >> 4, n4 = (idx & 15) * 4;
            float4 v = *(const float4*)&S[(size_t)(k0 + tk * 64 + k) * ld_src +
                                          n0 + tn * 64 + n4];
            *(uint32_t*)&sT[k * 66 + n4]     = pack2(v.x, v.y);
            *(uint32_t*)&sT[k * 66 + n4 + 2] = pack2(v.z, v.w);
        }
        __syncthreads();
#pragma unroll
        for (int j = 0; j < 2; j++) {
            int idx = t + j * 256;               // 0..511
            int n = idx >> 3, kq = idx & 7;
            union { bf16 h[8]; uint4 u; } pk;
#pragma unroll
            for (int jj = 0; jj < 8; jj++) pk.h[jj] = sT[(kq * 8 + jj) * 66 + n];
            int ng = tn * 64 + n;
            int ch = kq ^ (ng & 7);              // swizzle within 64-elem segment
            *(uint4*)&D[(size_t)ng * KL + tk * 64 + ch * 8] = pk.u;
        }
    }
}

// ---------------- FFN1: H[:, :CW](swz) = relu(Xg @ W1t' + b1) --------------
// 128x128 tile, single-buffer staging (32 KB -> 5 blk/CU), LDS-repacked
// vector C-write reusing the same 32 KB.
__global__ __launch_bounds__(256) void k_ffn1n(const bf16* __restrict__ Xg,
                                               const bf16* __restrict__ W1t,
                                               const float* __restrict__ b1,
                                               const int* __restrict__ wsi,
                                               bf16* __restrict__ H,
                                               int h0, int CW) {
    int gx = gridDim.x;
    int orig = blockIdx.x + gx * blockIdx.y;
    int wgid = xcd_remap(orig, gx * gridDim.y);
    int bx = wgid % gx, tile = wgid / gx;
    if (tile >= wsi[WS_NTILES / 4]) return;
    int e    = wsi[WS_TILE_E / 4 + tile];
    int row0 = wsi[WS_TILE_R / 4 + tile];
    int n0   = bx * BN;                      // within chunk

    const bf16* Abase = Xg + (size_t)row0 * IDIM;
    const bf16* Bbase = W1t + ((size_t)e * CW + n0) * IDIM;

    __shared__ bf16 smem[BM * BK + BN * BK]; // 32 KB total
    bf16* sA = smem;
    bf16* sB = smem + BM * BK;

    int t = threadIdx.x, lane = t & 63;
    int wv = t >> 6, wx = wv & 1, wy = wv >> 1;
    int lm = lane & 15, q = lane >> 4;

    f32x4 acc[4][4];
#pragma unroll
    for (int i = 0; i < 4; i++)
#pragma unroll
        for (int j = 0; j < 4; j++) acc[i][j] = (f32x4){0.f, 0.f, 0.f, 0.f};

    for (int kc = 0; kc < IDIM / BK; kc++) {
        if (kc) __syncthreads();
#pragma unroll
        for (int i = 0; i < 4; i++) {
            int s = t + i * 256;
            g2l16(Abase + (size_t)(s >> 3) * IDIM + kc * BK + (s & 7) * 8,
                  &sA[s * 8]);
        }
#pragma unroll
        for (int i = 0; i < 4; i++) {
            int s = t + i * 256;
            g2l16(Bbase + (size_t)(s >> 3) * IDIM + kc * BK + (s & 7) * 8,
                  &sB[s * 8]);
        }
        __syncthreads();
#pragma unroll
        for (int ks = 0; ks < 2; ks++) {
            bf16x8 aF[4], bF[4];
#pragma unroll
            for (int mt = 0; mt < 4; mt++) {
                int r = wy * 64 + mt * 16 + lm;
                aF[mt] = *(const bf16x8*)&sA[r * BK + (((ks * 4 + q) ^ (r & 7)) * 8)];
            }
#pragma unroll
            for (int nt = 0; nt < 4; nt++) {
                int r = wx * 64 + nt * 16 + lm;
                bF[nt] = *(const bf16x8*)&sB[r * BK + (((ks * 4 + q) ^ (r & 7)) * 8)];
            }
#pragma unroll
            for (int mt = 0; mt < 4; mt++)
#pragma unroll
                for (int nt = 0; nt < 4; nt++)
                    acc[mt][nt] = __builtin_amdgcn_mfma_f32_16x16x32_bf16(
                        aF[mt], bF[nt], acc[mt][nt], 0, 0, 0);
        }
    }

    // ---- epilogue: repack through LDS (same 32 KB), store uint4 coalesced --
    __syncthreads();
    bf16* sC = smem;                         // [128][128] bf16 = 32 KB
#pragma unroll
    for (int nt = 0; nt < 4; nt++) {
        int col_l = wx * 64 + nt * 16 + lm;  // local col 0..127
        float bv  = b1[(size_t)e * HID + h0 + n0 + col_l];
#pragma unroll
        for (int mt = 0; mt < 4; mt++) {
#pragma unroll
            for (int r = 0; r < 4; r++) {
                int rloc = wy * 64 + mt * 16 + q * 4 + r;
                int rg   = row0 + rloc;
                float v = fmaxf(acc[mt][nt][r] + bv, 0.f);
                int sc = (col_l & ~63) | ((col_l & 63) ^ ((rg & 7) << 3));
                sC[rloc * BN + sc] = (bf16)v;
            }
        }
    }
    __syncthreads();
#pragma unroll
    for (int i = 0; i < 8; i++) {
        int u = t + i * 256;                 // 0..2047
        int row = u >> 4, c = u & 15;
        uint4 v = *(const uint4*)&sC[row * BN + c * 8];
        *(uint4*)&H[(size_t)(row0 + row) * CW + n0 + c * 8] = v;
    }
}

// -------- FFN2: Y[row] (+)= H @ W2t' (+ b2 on first chunk); 2-phase dbuf ---
// LDS 48 KB; occupancy is grid-limited (~2.3 blk/CU) so dbuf is free here.
__global__ __launch_bounds__(256) void k_ffn2y(const bf16* __restrict__ H,
                                               const bf16* __restrict__ W2t,
                                               const float* __restrict__ b2,
                                               const int* __restrict__ wsi,
                                               float* __restrict__ Y,
                                               int CW, int first) {
    int gx = gridDim.x;
    int orig = blockIdx.x + gx * blockIdx.y;
    int wgid = xcd_remap(orig, gx * gridDim.y);
    int bx = wgid % gx, tile = wgid / gx;
    if (tile >= wsi[WS_NTILES / 4]) return;
    int e    = wsi[WS_TILE_E / 4 + tile];
    int row0 = wsi[WS_TILE_R / 4 + tile];
    int n0   = bx * BN2;

    const bf16* Abase = H + (size_t)row0 * CW;
    const bf16* Bbase = W2t + ((size_t)e * IDIM + n0) * CW;

    __shared__ bf16 sA[2][BM * BK];          // 2 x 16 KB
    __shared__ bf16 sB[2][BN2 * BK];         // 2 x 8 KB

    int t = threadIdx.x, lane = t & 63;
    int wv = t >> 6, wx = wv & 1, wy = wv >> 1;
    int lm = lane & 15, q = lane >> 4;

    f32x4 acc[4][2];
#pragma unroll
    for (int i = 0; i < 4; i++)
#pragma unroll
        for (int j = 0; j < 2; j++) acc[i][j] = (f32x4){0.f, 0.f, 0.f, 0.f};

    auto stage = [&](int kc, int b) {
#pragma unroll
        for (int i = 0; i < 4; i++) {
            int s = t + i * 256;
            g2l16(Abase + (size_t)(s >> 3) * CW + kc * BK + (s & 7) * 8,
                  &sA[b][s * 8]);
        }
#pragma unroll
        for (int i = 0; i < 2; i++) {
            int s = t + i * 256;
            g2l16(Bbase + (size_t)(s >> 3) * CW + kc * BK + (s & 7) * 8,
                  &sB[b][s * 8]);
        }
    };

    int kiters = CW / BK;
    stage(0, 0);
    __syncthreads();
    for (int kc = 0; kc < kiters; kc++) {
        int cur = kc & 1;
        if (kc + 1 < kiters) stage(kc + 1, cur ^ 1);
        const bf16* A = sA[cur];
        const bf16* B = sB[cur];
#pragma unroll
        for (int ks = 0; ks < 2; ks++) {
            bf16x8 aF[4], bF[2];
#pragma unroll
            for (int mt = 0; mt < 4; mt++) {
                int r = wy * 64 + mt * 16 + lm;
                aF[mt] = *(const bf16x8*)&A[r * BK + (((ks * 4 + q) ^ (r & 7)) * 8)];
            }
#pragma unroll
            for (int nt = 0; nt < 2; nt++) {
                int r = wx * 32 + nt * 16 + lm;
                bF[nt] = *(const bf16x8*)&B[r * BK + (((ks * 4 + q) ^ (r & 7)) * 8)];
            }
#pragma unroll
            for (int mt = 0; mt < 4; mt++)
#pragma unroll
                for (int nt = 0; nt < 2; nt++)
                    acc[mt][nt] = __builtin_amdgcn_mfma_f32_16x16x32_bf16(
                        aF[mt], bF[nt], acc[mt][nt], 0, 0, 0);
        }
        __syncthreads();
    }

#pragma unroll
    for (int nt = 0; nt < 2; nt++) {
        int col  = n0 + wx * 32 + nt * 16 + lm;
        float bv = first ? b2[(size_t)e * IDIM + col] : 0.f;
#pragma unroll
        for (int mt = 0; mt < 4; mt++)
#pragma unroll
            for (int r = 0; r < 4; r++) {
                int rg = row0 + wy * 64 + mt * 16 + q * 4 + r;
                float* p = &Y[(size_t)rg * IDIM + col];
                float v  = acc[mt][nt][r] + bv;
                *p = first ? v : (*p + v);
            }
    }
}

// -------- combine: out[tok] = w0*Y[pos0] + w1*Y[pos1]  (one block/token) ---
__global__ __launch_bounds__(256) void k_combine(const float* __restrict__ Y,
                                                 const int* __restrict__ wsi,
                                                 const float* __restrict__ wsf,
                                                 float* __restrict__ out) {
    int tok = blockIdx.x;
    int p0 = wsi[WS_TOK_POS / 4 + 2 * tok];
    int p1 = wsi[WS_TOK_POS / 4 + 2 * tok + 1];
    float w0 = wsf[WS_TOK_W / 4 + 2 * tok];
    float w1 = wsf[WS_TOK_W / 4 + 2 * tok + 1];
    int c = threadIdx.x;                    // float4 index within row (256)
    const float4* y0 = (const float4*)(Y + (size_t)p0 * IDIM);
    const float4* y1 = (const float4*)(Y + (size_t)p1 * IDIM);
    float4 a = y0[c], b = y1[c];
    float4 r;
    r.x = w0 * a.x + w1 * b.x;
    r.y = w0 * a.y + w1 * b.y;
    r.z = w0 * a.z + w1 * b.z;
    r.w = w0 * a.w + w1 * b.w;
    ((float4*)(out + (size_t)tok * IDIM))[c] = r;
}

// ---------------- zero-workspace fallback (fp32) ----------------
__global__ __launch_bounds__(256) void k_fallback(const float* __restrict__ xs,
                                                  const float* __restrict__ Wg,
                                                  const float* __restrict__ W1,
                                                  const float* __restrict__ b1,
                                                  const float* __restrict__ W2,
                                                  const float* __restrict__ b2,
                                                  float* __restrict__ out) {
    __shared__ float xbuf[IDIM];
    __shared__ float hbuf[256];
    __shared__ float slog[NE];
    __shared__ int   sel[2];
    __shared__ float selw[2];

    int t   = blockIdx.x;
    int tid = threadIdx.x;

    for (int i = tid; i < IDIM; i += 256)
        xbuf[i] = xs[(size_t)t * IDIM + i];
    __syncthreads();
    {
        int e = tid >> 5, l = tid & 31;
        float p = 0.f;
        for (int d = l; d < IDIM; d += 32)
            p += xbuf[d] * Wg[e * IDIM + d];
        for (int off = 16; off > 0; off >>= 1) p += __shfl_down(p, off, 32);
        if (l == 0) slog[e] = p;
    }
    __syncthreads();
    if (tid == 0) {
        int e0 = 0; float l0 = slog[0];
        for (int e = 1; e < NE; e++) if (slog[e] > l0) { l0 = slog[e]; e0 = e; }
        int e1 = -1; float l1 = -1e30f;
        for (int e = 0; e < NE; e++) if (e != e0 && slog[e] > l1) { l1 = slog[e]; e1 = e; }
        if (e1 < 0) e1 = (e0 + 1) & 7;
        float z = __expf(l1 - l0);
        sel[0] = e0; sel[1] = e1;
        selw[0] = 1.f / (1.f + z);
        selw[1] = z / (1.f + z);
    }
    __syncthreads();

    float ytot[4] = {0.f, 0.f, 0.f, 0.f};
#pragma unroll
    for (int s = 0; s < 2; s++) {
        int   e = sel[s];
        float w = selw[s];
        const float* W1e = W1 + (size_t)e * IDIM * HID;
        const float* W2e = W2 + (size_t)e * HID * IDIM;
        float ys[4] = {0.f, 0.f, 0.f, 0.f};
        for (int hb = 0; hb < HID / 256; hb++) {
            int h = hb * 256 + tid;
            float acc = b1[e * HID + h];
            for (int d = 0; d < IDIM; d++)
                acc += xbuf[d] * W1e[(size_t)d * HID + h];
            __syncthreads();
            hbuf[tid] = fmaxf(acc, 0.f);
            __syncthreads();
            for (int hh = 0; hh < 256; hh++) {
                float hv = hbuf[hh];
                const float* wrow = W2e + (size_t)(hb * 256 + hh) * IDIM;
#pragma unroll
                for (int cc = 0; cc < 4; cc++)
                    ys[cc] += hv * wrow[cc * 256 + tid];
            }
        }
#pragma unroll
        for (int cc = 0; cc < 4; cc++)
            ytot[cc] += w * (ys[cc] + b2[e * IDIM + cc * 256 + tid]);
    }
#pragma unroll
    for (int cc = 0; cc < 4; cc++)
        out[(size_t)t * IDIM + cc * 256 + tid] = ytot[cc];
}

extern "C" void kernel_launch(void* const* d_in, const int* in_sizes, int n_in,
                              void* d_out, int out_size, void* d_ws, size_t ws_size,
                              hipStream_t stream) {
    int o = (n_in >= 7 && in_sizes[1] == 1) ? 1 : 0;
    const float* xs = (const float*)d_in[0];
    const float* Wg = (const float*)d_in[1 + o];
    const float* W1 = (const float*)d_in[2 + o];
    const float* b1 = (const float*)d_in[3 + o];
    const float* W2 = (const float*)d_in[4 + o];
    const float* b2 = (const float*)d_in[5 + o];
    float* out = (float*)d_out;

    // tier: meta + Xg + H(RMAX*CW) + Wshared(NE*CW*IDIM) + Y(RMAX*IDIM*4).
    size_t xg_sz = (size_t)RMAX * IDIM * 2;
    size_t y_sz  = (size_t)RMAX * IDIM * 4;
    int CW = 0;
    if (d_ws) {
        for (int c = HID; c >= 512; c >>= 1) {
            size_t need = (size_t)XG_OFF + xg_sz + (size_t)RMAX * c * 2 +
                          (size_t)NE * c * IDIM * 2 + y_sz;
            if (ws_size >= need) { CW = c; break; }
        }
    }
    if (!CW) {
        k_fallback<<<T_TOK, 256, 0, stream>>>(xs, Wg, W1, b1, W2, b2, out);
        return;
    }

    char*  ws  = (char*)d_ws;
    int*   wsi = (int*)d_ws;
    float* wsf = (float*)d_ws;
    bf16*  Xg  = (bf16*)(ws + XG_OFF);
    bf16*  Hb  = (bf16*)(ws + XG_OFF + xg_sz);
    bf16*  Wt  = (bf16*)(ws + XG_OFF + xg_sz + (size_t)RMAX * CW * 2);
    float* Yb  = (float*)(ws + XG_OFF + xg_sz + (size_t)RMAX * CW * 2 +
                          (size_t)NE * CW * IDIM * 2);

    k_router<<<T_TOK / 4, 256, 0, stream>>>(xs, Wg, wsi + WS_TOK_E / 4,
                                            wsf + WS_TOK_W / 4);
    k_setup<<<1, 256, 0, stream>>>(wsi, wsf);
    k_gather<<<RMAX / 4, 256, 0, stream>>>(xs, wsi, Xg);

    int HC = HID / CW;
    for (int c = 0; c < HC; c++) {
        // W1 chunk: src [k=IDIM][n=HID] -> Wt [n_local(CW)][k(IDIM)]
        {
            int ntn = CW / 64, ntk = IDIM / 64;
            int tpb = ntk;
            while (ntn * NE * (ntk / tpb) < 1024 && tpb > 1) tpb >>= 1;
            k_cvt<<<dim3(ntn, ntk / tpb, NE), 256, 0, stream>>>(
                W1, Wt, HID, 0, c * CW, IDIM,
                (size_t)IDIM * HID, (size_t)CW * IDIM, tpb);
        }
        k_ffn1n<<<dim3(CW / BN, MAXTILES), 256, 0, stream>>>(
            Xg, Wt, b1, wsi, Hb, c * CW, CW);
        // W2 chunk: src [k=HID][n=IDIM] -> Wt [n(IDIM)][k_local(CW)]
        {
            int ntn = IDIM / 64, ntk = CW / 64;
            int tpb = ntk;
            while (ntn * NE * (ntk / tpb) < 1024 && tpb > 1) tpb >>= 1;
            k_cvt<<<dim3(ntn, ntk / tpb, NE), 256, 0, stream>>>(
                W2, Wt, IDIM, c * CW, 0, CW,
                (size_t)HID * IDIM, (size_t)IDIM * CW, tpb);
        }
        k_ffn2y<<<dim3(IDIM / BN2, MAXTILES), 256, 0, stream>>>(
            Hb, Wt, b2, wsi, Yb, CW, c == 0 ? 1 : 0);
    }
    k_combine<<<T_TOK, 256, 0, stream>>>(Yb, wsi, wsf, out);
}